// Round 11
// baseline (268.449 us; speedup 1.0000x reference)
//
#include <hip/hip_runtime.h>
#include <hip/hip_bf16.h>

typedef __hip_bfloat16 bf16;
typedef __attribute__((ext_vector_type(8))) short short8;
typedef __attribute__((ext_vector_type(4))) float f32x4;

static __device__ __forceinline__ float lrelu(float x){ return x > 0.f ? x : 0.2f * x; }

static __device__ __forceinline__ float ldf(const void* p, size_t i, int f32){
  return f32 ? ((const float*)p)[i] : __bfloat162float(((const bf16*)p)[i]);
}

static __device__ __forceinline__ float wsum(float v){
#pragma unroll
  for (int o = 32; o; o >>= 1) v += __shfl_xor(v, o, 64);
  return v;
}
static __device__ __forceinline__ float qsum(float v){
  v += __shfl_xor(v, 1); v += __shfl_xor(v, 2);
  v += __shfl_xor(v, 4); v += __shfl_xor(v, 8);
  return v;
}

static __device__ __forceinline__ unsigned short f2bf(float x){
  unsigned u = __float_as_uint(x);
  unsigned r = (u + 0x7fffu + ((u >> 16) & 1u)) >> 16;
  return (unsigned short)r;
}
static __device__ __forceinline__ float bfval(unsigned short h){
  return __uint_as_float(((unsigned)h) << 16);
}
static __device__ __forceinline__ unsigned packbf2(float a, float b){
  return ((unsigned)f2bf(b) << 16) | (unsigned)f2bf(a);
}
static __device__ __forceinline__ float unlo(unsigned v){ return __uint_as_float(v << 16); }
static __device__ __forceinline__ float unhi(unsigned v){ return __uint_as_float(v & 0xffff0000u); }

// ---------------- constants ----------------
#define CAP 10240          // binned slots per bucket (mean 8418, ~20 sigma)
#define EPB 16             // edges per thread in binscatter
#define CHUNK (256 * EPB)  // 4096 edges per block
#define PREPB 96           // prepw blocks in launch A
#define SORTCAP 9216       // LDS sort staging (8.7 sigma; global fallback beyond)

// ---------------- Launch A: prepw2 (blocks 0..95, self-detect) || binscatter ----------------
__global__ __launch_bounds__(256) void k_prep_scatter(
    const unsigned short* __restrict__ xprobe,
    const void* __restrict__ W1, const void* __restrict__ W2,
    int* __restrict__ flag,
    unsigned short* __restrict__ w1hi, unsigned short* __restrict__ w1lo,
    unsigned short* __restrict__ w2hi, unsigned short* __restrict__ w2lo,
    const int* __restrict__ ei, int* __restrict__ bucketCur,
    unsigned* __restrict__ binned, int E, int Etot){
  __shared__ int lcnt[256];
  __shared__ int lcur[256];
  int t = threadIdx.x;
  if (blockIdx.x < PREPB){
    // --- dtype probe: 512 halfwords of x. f32-as-bf16 trips ~123; true bf16 trips 0. ---
    if (t == 0) lcnt[0] = 0;
    __syncthreads();
    int bad = 0;
    for (int i = t; i < 512; i += 256){
      int e = (xprobe[i] >> 7) & 0xFF;
      if (e >= 133) bad++;
    }
    if (bad) atomicAdd(&lcnt[0], bad);
    __syncthreads();
    const int f = lcnt[0] > 8;
    if (blockIdx.x == 0 && t == 0) *flag = f;
    // --- prepw body ---
    int blk = blockIdx.x;
    const void* W; unsigned short *hi, *lo; int ncol, nct, tg;
    if (blk < 64){ W = W1; hi = w1hi; lo = w1lo; ncol = 128; nct = 8; tg = blk * 256 + t; }
    else         { W = W2; hi = w2hi; lo = w2lo; ncol = 64;  nct = 4; tg = (blk - 64) * 256 + t; }
    int j = tg & 7;
    int lane = (tg >> 3) & 63;
    int ct = (tg >> 9) % nct;
    int kc = tg / (512 * nct);
    int k = kc * 32 + ((lane >> 4) << 3) + j;
    int col = ct * 16 + (lane & 15);
    float w = ldf(W, (size_t)k * ncol + col, f);
    unsigned short h = f2bf(w);
    hi[tg] = h;
    lo[tg] = f2bf(w - bfval(h));
  } else {
    // --- binscatter body ---
    lcnt[t] = 0;
    __syncthreads();
    int base = (blockIdx.x - PREPB) * CHUNK;
    int vsrc[EPB], vdst[EPB];
#pragma unroll
    for (int k = 0; k < EPB; k++){
      int i = base + k * 256 + t;
      vdst[k] = -1;
      if (i < Etot){
        if (i < E){ vsrc[k] = ei[i]; vdst[k] = ei[E + i]; }
        else { vsrc[k] = i - E; vdst[k] = i - E; }
        atomicAdd(&lcnt[vdst[k] >> 8], 1);
      }
    }
    __syncthreads();
    lcur[t] = lcnt[t] ? atomicAdd(&bucketCur[t], lcnt[t]) : 0;
    __syncthreads();
#pragma unroll
    for (int k = 0; k < EPB; k++){
      if (vdst[k] >= 0){
        int b = vdst[k] >> 8;
        int p = atomicAdd(&lcur[b], 1);
        binned[(size_t)b * CAP + p] = (unsigned)vsrc[k] | ((unsigned)(vdst[k] & 255) << 24);
      }
    }
  }
}

// ---------------- Launch B: bucketsort (blocks 0..NBUCK-1) || gemm1m (MFMA bf16x3) ----------------
__global__ __launch_bounds__(256) void k_sort_gemm1(
    const int* __restrict__ bucketCur, const unsigned* __restrict__ binned,
    int* __restrict__ deg, int* __restrict__ offs, int* __restrict__ csr, int nbuck,
    const void* __restrict__ x,
    const unsigned short* __restrict__ whi, const unsigned short* __restrict__ wlo,
    const void* __restrict__ a_src1, const void* __restrict__ a_dst1,
    const int* __restrict__ flagp,
    unsigned* __restrict__ xh1p, float* __restrict__ ssrc1, float* __restrict__ sdst1, int n){
  __shared__ int smem[768 + SORTCAP];   // 39936 B: lcnt | lsc | lcur | lsrc
  int t = threadIdx.x;
  if ((int)blockIdx.x < nbuck){
    int* lcnt = smem;
    int* lsc  = smem + 256;
    int* lcur = smem + 512;
    int* lsrc = smem + 768;
    int b = blockIdx.x;
    int s0 = b * CAP;
    int cnt = bucketCur[b];
    int node0 = b << 8;
    lcnt[t] = 0;
    __syncthreads();
    for (int i = t; i < cnt; i += 256){
      unsigned v = binned[s0 + i];
      atomicAdd(&lcnt[v >> 24], 1);
    }
    __syncthreads();
    lsc[t] = lcnt[t];
    __syncthreads();
#pragma unroll
    for (int o = 1; o < 256; o <<= 1){
      int xv = (t >= o) ? lsc[t - o] : 0;
      __syncthreads();
      lsc[t] += xv;
      __syncthreads();
    }
    int excl = lsc[t] - lcnt[t];
    int node = node0 + t;
    if (node < n){ deg[node] = lcnt[t]; offs[node] = s0 + excl; }
    lcur[t] = excl;
    __syncthreads();
    if (cnt <= SORTCAP){
      for (int i = t; i < cnt; i += 256){
        unsigned v = binned[s0 + i];
        int p = atomicAdd(&lcur[v >> 24], 1);
        lsrc[p] = (int)(v & 0xFFFFFFu);
      }
      __syncthreads();
      for (int i = t; i < cnt; i += 256) csr[s0 + i] = lsrc[i];
    } else {
      for (int i = t; i < cnt; i += 256){
        unsigned v = binned[s0 + i];
        int p = atomicAdd(&lcur[v >> 24], 1);
        csr[s0 + p] = (int)(v & 0xFFFFFFu);
      }
    }
  } else {
    // --- gemm1m body ---
    const int f = *flagp;
    int lane = t & 63, w = t >> 6;
    int c16 = lane & 15, quad = lane >> 4;
    int nbw = (blockIdx.x - nbuck) * 64 + w * 16;
    int an = min(nbw + c16, n - 1);
    f32x4 acc[8];
#pragma unroll
    for (int ct = 0; ct < 8; ct++)
#pragma unroll
      for (int r = 0; r < 4; r++) acc[ct][r] = 0.f;

#pragma unroll
    for (int kc = 0; kc < 4; kc++){
      float av[8];
      short8 ahi, alo;
      if (f){
        const float* row = (const float*)x + (size_t)an * 128 + kc * 32 + quad * 8;
        float4 v0 = *(const float4*)row;
        float4 v1 = *(const float4*)(row + 4);
        av[0] = v0.x; av[1] = v0.y; av[2] = v0.z; av[3] = v0.w;
        av[4] = v1.x; av[5] = v1.y; av[6] = v1.z; av[7] = v1.w;
#pragma unroll
        for (int j = 0; j < 8; j++){
          unsigned short h = f2bf(av[j]);
          ahi[j] = (short)h;
          alo[j] = (short)f2bf(av[j] - bfval(h));
        }
      } else {
        const unsigned short* row = (const unsigned short*)x + (size_t)an * 128 + kc * 32 + quad * 8;
        uint4 v = *(const uint4*)row;
        ahi[0] = (short)(v.x & 0xffff); ahi[1] = (short)(v.x >> 16);
        ahi[2] = (short)(v.y & 0xffff); ahi[3] = (short)(v.y >> 16);
        ahi[4] = (short)(v.z & 0xffff); ahi[5] = (short)(v.z >> 16);
        ahi[6] = (short)(v.w & 0xffff); ahi[7] = (short)(v.w >> 16);
#pragma unroll
        for (int j = 0; j < 8; j++) alo[j] = 0;
      }
#pragma unroll
      for (int ct = 0; ct < 8; ct++){
        const short8 bhi = *(const short8*)(whi + (((size_t)(kc * 8 + ct) * 64 + lane) << 3));
        const short8 blo = *(const short8*)(wlo + (((size_t)(kc * 8 + ct) * 64 + lane) << 3));
        acc[ct] = __builtin_amdgcn_mfma_f32_16x16x32_bf16(ahi, blo, acc[ct], 0, 0, 0);
        acc[ct] = __builtin_amdgcn_mfma_f32_16x16x32_bf16(alo, bhi, acc[ct], 0, 0, 0);
        acc[ct] = __builtin_amdgcn_mfma_f32_16x16x32_bf16(ahi, bhi, acc[ct], 0, 0, 0);
      }
    }

    float as[8], ad[8];
#pragma unroll
    for (int ct = 0; ct < 8; ct++){
      as[ct] = ldf(a_src1, ct * 16 + c16, f);
      ad[ct] = ldf(a_dst1, ct * 16 + c16, f);
    }
    float vs0[4], vs1[4], vd0[4], vd1[4];
#pragma unroll
    for (int r = 0; r < 4; r++){
      float s0 = 0.f, s1 = 0.f, d0 = 0.f, d1 = 0.f;
#pragma unroll
      for (int ct = 0; ct < 4; ct++){
        s0 += acc[ct][r] * as[ct];         d0 += acc[ct][r] * ad[ct];
        s1 += acc[ct + 4][r] * as[ct + 4]; d1 += acc[ct + 4][r] * ad[ct + 4];
      }
      vs0[r] = qsum(s0); vs1[r] = qsum(s1);
      vd0[r] = qsum(d0); vd1[r] = qsum(d1);
    }
#pragma unroll
    for (int r = 0; r < 4; r++){
      int node = nbw + quad * 4 + r;
      if (node < n){
#pragma unroll
        for (int ct = 0; ct < 4; ct++)
          xh1p[(size_t)node * 64 + ct * 16 + c16] = packbf2(acc[ct][r], acc[ct + 4][r]);
      }
    }
    if (c16 == 0){
#pragma unroll
      for (int r = 0; r < 4; r++){
        int node = nbw + quad * 4 + r;
        if (node < n){
          ssrc1[node * 2]     = vs0[r];
          ssrc1[node * 2 + 1] = vs1[r];
          sdst1[node * 2]     = vd0[r];
          sdst1[node * 2 + 1] = vd1[r];
        }
      }
    }
  }
}

// ---------------- Layer-2 GEMM via MFMA: xh2 = h1(bf16) @ W2(hi+lo) + logits ----------------
__global__ __launch_bounds__(256) void k_gemm2m(
    const unsigned* __restrict__ h1p,
    const unsigned short* __restrict__ whi, const unsigned short* __restrict__ wlo,
    const void* __restrict__ a_src2, const void* __restrict__ a_dst2,
    const int* __restrict__ flagp,
    unsigned short* __restrict__ xh2b, float* __restrict__ ssrc2, float* __restrict__ sdst2, int n){
  const int f = *flagp;
  int t = threadIdx.x;
  int lane = t & 63, w = t >> 6;
  int c16 = lane & 15, quad = lane >> 4;
  int nbw = blockIdx.x * 64 + w * 16;
  int an = min(nbw + c16, n - 1);
  f32x4 acc[4];
#pragma unroll
  for (int ct = 0; ct < 4; ct++)
#pragma unroll
    for (int r = 0; r < 4; r++) acc[ct][r] = 0.f;

#pragma unroll
  for (int kc = 0; kc < 4; kc++){
    const uint4* hp = (const uint4*)h1p;
    uint4 v = hp[(size_t)an * 16 + kc * 4 + quad];
    short8 ahi;
    ahi[0] = (short)(v.x & 0xffff); ahi[1] = (short)(v.x >> 16);
    ahi[2] = (short)(v.y & 0xffff); ahi[3] = (short)(v.y >> 16);
    ahi[4] = (short)(v.z & 0xffff); ahi[5] = (short)(v.z >> 16);
    ahi[6] = (short)(v.w & 0xffff); ahi[7] = (short)(v.w >> 16);
#pragma unroll
    for (int ct = 0; ct < 4; ct++){
      const short8 bhi = *(const short8*)(whi + (((size_t)(kc * 4 + ct) * 64 + lane) << 3));
      const short8 blo = *(const short8*)(wlo + (((size_t)(kc * 4 + ct) * 64 + lane) << 3));
      acc[ct] = __builtin_amdgcn_mfma_f32_16x16x32_bf16(ahi, blo, acc[ct], 0, 0, 0);
      acc[ct] = __builtin_amdgcn_mfma_f32_16x16x32_bf16(ahi, bhi, acc[ct], 0, 0, 0);
    }
  }

  float as[4], ad[4];
#pragma unroll
  for (int ct = 0; ct < 4; ct++){
    as[ct] = ldf(a_src2, ct * 16 + c16, f);
    ad[ct] = ldf(a_dst2, ct * 16 + c16, f);
  }
  float vs[4], vd[4];
#pragma unroll
  for (int r = 0; r < 4; r++){
    float s = 0.f, d = 0.f;
#pragma unroll
    for (int ct = 0; ct < 4; ct++){
      s += acc[ct][r] * as[ct];
      d += acc[ct][r] * ad[ct];
    }
    vs[r] = qsum(s); vd[r] = qsum(d);
  }
#pragma unroll
  for (int r = 0; r < 4; r++){
    int node = nbw + quad * 4 + r;
    if (node < n){
#pragma unroll
      for (int ct = 0; ct < 4; ct++)
        xh2b[(size_t)node * 64 + ct * 16 + c16] = f2bf(acc[ct][r]);
    }
  }
  if (c16 == 0){
#pragma unroll
    for (int r = 0; r < 4; r++){
      int node = nbw + quad * 4 + r;
      if (node < n){ ssrc2[node] = vs[r]; sdst2[node] = vd[r]; }
    }
  }
}

// ---------------- Layer-1 aggregation: flat softmax, LDS-staged, QUARTER-wave gather (uint4) ----------------
// lane (quarter, u): handles channels {4u..4u+3} x both heads of its quarter's edge; 4 edges/step.
__global__ __launch_bounds__(256) void k_agg1(
    const int* __restrict__ offs, const int* __restrict__ deg, const int* __restrict__ csr,
    const float2* __restrict__ ssrc, const float2* __restrict__ sdst,
    const unsigned* __restrict__ xh1p, const void* __restrict__ b1,
    const int* __restrict__ flagp, unsigned* __restrict__ h1p, int n){
  __shared__ float4 stg[4][64];   // wave-private (s, p0, p1, -) per chunk edge
  int wv = threadIdx.x >> 6;
  int wid = (int)(((size_t)blockIdx.x * blockDim.x + threadIdx.x) >> 6);
  int lane = threadIdx.x & 63;
  if (wid >= n) return;
  int st = offs[wid], d = deg[wid];
  int quarter = lane >> 4, u = lane & 15;
  float2 sd = sdst[wid];
  const uint4* xp = (const uint4*)xh1p;   // node*16+u -> packed channels {4u..4u+3}, both heads
  float Z0l = 0.f, Z1l = 0.f;
  float a0[4] = {0.f, 0.f, 0.f, 0.f};
  float a1[4] = {0.f, 0.f, 0.f, 0.f};
  for (int base = 0; base < d; base += 64){
    int idx = base + lane;
    bool val = idx < d;
    int s = csr[st + (val ? idx : 0)];
    float2 sv = ssrc[s];
    float e0 = fminf(lrelu(sv.x + sd.x), 80.f);
    float e1 = fminf(lrelu(sv.y + sd.y), 80.f);
    float p0 = val ? __expf(e0) : 0.f;
    float p1 = val ? __expf(e1) : 0.f;
    Z0l += p0; Z1l += p1;
    float4 tv; tv.x = __uint_as_float((unsigned)s); tv.y = p0; tv.z = p1; tv.w = 0.f;
    stg[wv][lane] = tv;
    int cnt = min(64, d - base);
    int groups = (cnt + 3) >> 2;            // <= 16; edge jj = 4*(g+k)+quarter <= 63
    for (int g = 0; g < groups; g += 4){
      int sj[4]; float q0v[4], q1v[4]; uint4 vv[4];
#pragma unroll
      for (int k = 0; k < 4; k++){
        int jj = ((g + k) << 2) + quarter;
        float4 v = stg[wv][jj];
        sj[k] = (int)__float_as_uint(v.x);
        q0v[k] = v.y; q1v[k] = v.z;
      }
#pragma unroll
      for (int k = 0; k < 4; k++)
        vv[k] = xp[(size_t)(unsigned)sj[k] * 16 + u];
#pragma unroll
      for (int k = 0; k < 4; k++){
        a0[0] = fmaf(q0v[k], unlo(vv[k].x), a0[0]); a1[0] = fmaf(q1v[k], unhi(vv[k].x), a1[0]);
        a0[1] = fmaf(q0v[k], unlo(vv[k].y), a0[1]); a1[1] = fmaf(q1v[k], unhi(vv[k].y), a1[1]);
        a0[2] = fmaf(q0v[k], unlo(vv[k].z), a0[2]); a1[2] = fmaf(q1v[k], unhi(vv[k].z), a1[2]);
        a0[3] = fmaf(q0v[k], unlo(vv[k].w), a0[3]); a1[3] = fmaf(q1v[k], unhi(vv[k].w), a1[3]);
      }
    }
  }
  // combine the 4 quarter partial sums
#pragma unroll
  for (int c = 0; c < 4; c++){
    a0[c] += __shfl_xor(a0[c], 16); a0[c] += __shfl_xor(a0[c], 32);
    a1[c] += __shfl_xor(a1[c], 16); a1[c] += __shfl_xor(a1[c], 32);
  }
  float Z0 = wsum(Z0l), Z1 = wsum(Z1l);
  const int f = *flagp;
  float i0 = 1.f / (Z0 + 1e-16f);
  float i1 = 1.f / (Z1 + 1e-16f);
  // quarter 0 writes head0 ch {4u..4u+3}; quarter 1 writes head1 (pair layout: pair c <-> ch {2c,2c+1})
  if (quarter == 0){
    float o0 = fmaxf(a0[0] * i0 + ldf(b1, 4 * u + 0, f), 0.f);
    float o1 = fmaxf(a0[1] * i0 + ldf(b1, 4 * u + 1, f), 0.f);
    float o2 = fmaxf(a0[2] * i0 + ldf(b1, 4 * u + 2, f), 0.f);
    float o3 = fmaxf(a0[3] * i0 + ldf(b1, 4 * u + 3, f), 0.f);
    uint2 sv; sv.x = packbf2(o0, o1); sv.y = packbf2(o2, o3);
    *(uint2*)&h1p[(size_t)wid * 64 + 2 * u] = sv;
  } else if (quarter == 1){
    float o0 = fmaxf(a1[0] * i1 + ldf(b1, 64 + 4 * u + 0, f), 0.f);
    float o1 = fmaxf(a1[1] * i1 + ldf(b1, 64 + 4 * u + 1, f), 0.f);
    float o2 = fmaxf(a1[2] * i1 + ldf(b1, 64 + 4 * u + 2, f), 0.f);
    float o3 = fmaxf(a1[3] * i1 + ldf(b1, 64 + 4 * u + 3, f), 0.f);
    uint2 sv; sv.x = packbf2(o0, o1); sv.y = packbf2(o2, o3);
    *(uint2*)&h1p[(size_t)wid * 64 + 32 + 2 * u] = sv;
  }
}

// ---------------- Layer-2 aggregation + fused heads: flat softmax, LDS-staged, QUARTER-wave (uint2) ----------------
__global__ __launch_bounds__(256) void k_agg2(
    const int* __restrict__ offs, const int* __restrict__ deg, const int* __restrict__ csr,
    const float* __restrict__ ssrc, const float* __restrict__ sdstA,
    const unsigned short* __restrict__ xh2b, const void* __restrict__ bias2,
    const void* __restrict__ Wm, const void* __restrict__ bm,
    const void* __restrict__ Wlos, const void* __restrict__ bl,
    const int* __restrict__ flagp, void* __restrict__ out, int n){
  __shared__ float2 stg[4][64];   // wave-private (s, p)
  int wv = threadIdx.x >> 6;
  int wid = (int)(((size_t)blockIdx.x * blockDim.x + threadIdx.x) >> 6);
  int lane = threadIdx.x & 63;
  if (wid >= n) return;
  int st = offs[wid], d = deg[wid];
  int quarter = lane >> 4, u = lane & 15;
  float sd = sdstA[wid];
  const uint2* xp = (const uint2*)xh2b;   // node*16+u -> channels {4u..4u+3}
  float Zl = 0.f;
  float ax[4] = {0.f, 0.f, 0.f, 0.f};
  for (int base = 0; base < d; base += 64){
    int idx = base + lane;
    bool val = idx < d;
    int s = csr[st + (val ? idx : 0)];
    float e = fminf(lrelu(ssrc[s] + sd), 80.f);
    float p = val ? __expf(e) : 0.f;
    Zl += p;
    float2 tv; tv.x = __uint_as_float((unsigned)s); tv.y = p;
    stg[wv][lane] = tv;
    int cnt = min(64, d - base);
    int groups = (cnt + 3) >> 2;
    for (int g = 0; g < groups; g += 4){
      int sj[4]; float qv[4]; uint2 vv[4];
#pragma unroll
      for (int k = 0; k < 4; k++){
        int jj = ((g + k) << 2) + quarter;
        float2 v = stg[wv][jj];
        sj[k] = (int)__float_as_uint(v.x);
        qv[k] = v.y;
      }
#pragma unroll
      for (int k = 0; k < 4; k++)
        vv[k] = xp[(size_t)(unsigned)sj[k] * 16 + u];
#pragma unroll
      for (int k = 0; k < 4; k++){
        ax[0] = fmaf(qv[k], unlo(vv[k].x), ax[0]); ax[1] = fmaf(qv[k], unhi(vv[k].x), ax[1]);
        ax[2] = fmaf(qv[k], unlo(vv[k].y), ax[2]); ax[3] = fmaf(qv[k], unhi(vv[k].y), ax[3]);
      }
    }
  }
#pragma unroll
  for (int c = 0; c < 4; c++){
    ax[c] += __shfl_xor(ax[c], 16);
    ax[c] += __shfl_xor(ax[c], 32);
  }
  float Z = wsum(Zl);
  const int f = *flagp;
  float inv = 1.f / (Z + 1e-16f);
  float hv[4];
#pragma unroll
  for (int c = 0; c < 4; c++)
    hv[c] = fmaxf(ax[c] * inv + ldf(bias2, 4 * u + c, f), 0.f);
  // heads: each channel counted once (quarter 0 lanes)
  float pm = 0.f, p0 = 0.f, p1 = 0.f, p2 = 0.f, p3 = 0.f;
  if (quarter == 0){
#pragma unroll
    for (int c = 0; c < 4; c++){
      int ch = 4 * u + c;
      pm += hv[c] * ldf(Wm, ch, f);
      p0 += hv[c] * ldf(Wlos, ch * 4 + 0, f);
      p1 += hv[c] * ldf(Wlos, ch * 4 + 1, f);
      p2 += hv[c] * ldf(Wlos, ch * 4 + 2, f);
      p3 += hv[c] * ldf(Wlos, ch * 4 + 3, f);
    }
  }
  float mo = wsum(pm);
  float l0 = wsum(p0), l1 = wsum(p1), l2 = wsum(p2), l3 = wsum(p3);
  if (lane == 0){
    float vm = mo + ldf(bm, 0, f);
    float v0 = l0 + ldf(bl, 0, f);
    float v1 = l1 + ldf(bl, 1, f);
    float v2 = l2 + ldf(bl, 2, f);
    float v3 = l3 + ldf(bl, 3, f);
    if (f){
      float* o = (float*)out;
      o[wid] = vm;
      float4 lv = make_float4(v0, v1, v2, v3);
      *(float4*)&o[n + wid * 4] = lv;
    } else {
      bf16* o = (bf16*)out;
      o[wid] = __float2bfloat16(vm);
      o[n + wid * 4 + 0] = __float2bfloat16(v0); o[n + wid * 4 + 1] = __float2bfloat16(v1);
      o[n + wid * 4 + 2] = __float2bfloat16(v2); o[n + wid * 4 + 3] = __float2bfloat16(v3);
    }
  }
}

extern "C" void kernel_launch(void* const* d_in, const int* in_sizes, int n_in,
                              void* d_out, int out_size, void* d_ws, size_t ws_size,
                              hipStream_t stream){
  const void* x      = d_in[0];
  const int*  ei     = (const int*)d_in[1];
  const void* W1     = d_in[2];
  const void* a_src1 = d_in[3];
  const void* a_dst1 = d_in[4];
  const void* b1     = d_in[5];
  const void* W2     = d_in[6];
  const void* a_src2 = d_in[7];
  const void* a_dst2 = d_in[8];
  const void* bias2  = d_in[9];
  const void* Wm     = d_in[10];
  const void* bm     = d_in[11];
  const void* Wlos   = d_in[12];
  const void* bl     = d_in[13];

  const int N = in_sizes[0] / 128;
  const int E = in_sizes[1] / 2;
  const int Etot = E + N;
  const int NBUCK = (N + 255) >> 8;

  char* base = (char*)d_ws;
  size_t off = 0;
  auto alloc = [&](size_t bytes) -> void* {
    void* r = base + off;
    off += (bytes + 255) & ~(size_t)255;
    return r;
  };
  int*      flag  = (int*)alloc(256);
  unsigned* xh1p  = (unsigned*)alloc((size_t)N * 64 * 4);   // packed bf16x2 (both heads)
  unsigned* h1p   = (unsigned*)alloc((size_t)N * 64 * 4);   // h1 packed bf16 pairs
  float*    ssrc1 = (float*)alloc((size_t)N * 2 * 4);
  float*    sdst1 = (float*)alloc((size_t)N * 2 * 4);
  float*    ssrc2 = (float*)alloc((size_t)N * 4);
  float*    sdst2 = (float*)alloc((size_t)N * 4);
  int*      deg    = (int*)alloc((size_t)N * 4);
  int*      offsb  = (int*)alloc((size_t)N * 4);
  unsigned* binned = (unsigned*)alloc((size_t)NBUCK * CAP * 4);
  int*      csr    = (int*)alloc((size_t)NBUCK * CAP * 4);
  int*      bucketCur = (int*)alloc(1024);
  unsigned short* w1hi = (unsigned short*)alloc(16384 * 2);
  unsigned short* w1lo = (unsigned short*)alloc(16384 * 2);
  unsigned short* w2hi = (unsigned short*)alloc(8192 * 2);
  unsigned short* w2lo = (unsigned short*)alloc(8192 * 2);
  unsigned short* xh2b = (unsigned short*)xh1p;   // reuse after k_agg1

  const int nchunk = (Etot + CHUNK - 1) / CHUNK;
  const int ngemm1 = (N + 63) / 64;

  // zero bucket cursors (stream op, capture-safe)
  hipMemsetAsync(bucketCur, 0, (size_t)NBUCK * 4, stream);

  // Launch A: prepw2 (w/ inline dtype probe, flag publish) || binscatter
  k_prep_scatter<<<PREPB + nchunk, 256, 0, stream>>>(
      (const unsigned short*)x, W1, W2, flag, w1hi, w1lo, w2hi, w2lo,
      ei, bucketCur, binned, E, Etot);

  // Launch B: bucketsort || gemm1m
  k_sort_gemm1<<<NBUCK + ngemm1, 256, 0, stream>>>(
      bucketCur, binned, deg, offsb, csr, NBUCK,
      x, w1hi, w1lo, a_src1, a_dst1, flag, xh1p, ssrc1, sdst1, N);

  // Layer 1 aggregation (outputs packed bf16 h1)
  k_agg1<<<(N + 3) / 4, 256, 0, stream>>>(offsb, deg, csr, (const float2*)ssrc1, (const float2*)sdst1,
                                          xh1p, b1, flag, h1p, N);

  // Layer 2
  k_gemm2m<<<(N + 63) / 64, 256, 0, stream>>>(h1p, w2hi, w2lo, a_src2, a_dst2, flag, xh2b, ssrc2, sdst2, N);
  k_agg2<<<(N + 3) / 4, 256, 0, stream>>>(offsb, deg, csr, ssrc2, sdst2, xh2b, bias2,
                                          Wm, bm, Wlos, bl, flag, d_out, N);
}

// Round 12
// 256.817 us; speedup vs baseline: 1.0453x; 1.0453x over previous
//
#include <hip/hip_runtime.h>
#include <hip/hip_bf16.h>

typedef __hip_bfloat16 bf16;
typedef __attribute__((ext_vector_type(8))) short short8;
typedef __attribute__((ext_vector_type(4))) float f32x4;

static __device__ __forceinline__ float lrelu(float x){ return x > 0.f ? x : 0.2f * x; }

static __device__ __forceinline__ float ldf(const void* p, size_t i, int f32){
  return f32 ? ((const float*)p)[i] : __bfloat162float(((const bf16*)p)[i]);
}

static __device__ __forceinline__ float wsum(float v){
#pragma unroll
  for (int o = 32; o; o >>= 1) v += __shfl_xor(v, o, 64);
  return v;
}
static __device__ __forceinline__ float qsum(float v){
  v += __shfl_xor(v, 1); v += __shfl_xor(v, 2);
  v += __shfl_xor(v, 4); v += __shfl_xor(v, 8);
  return v;
}

static __device__ __forceinline__ unsigned short f2bf(float x){
  unsigned u = __float_as_uint(x);
  unsigned r = (u + 0x7fffu + ((u >> 16) & 1u)) >> 16;
  return (unsigned short)r;
}
static __device__ __forceinline__ float bfval(unsigned short h){
  return __uint_as_float(((unsigned)h) << 16);
}
static __device__ __forceinline__ unsigned packbf2(float a, float b){
  return ((unsigned)f2bf(b) << 16) | (unsigned)f2bf(a);
}
static __device__ __forceinline__ float unlo(unsigned v){ return __uint_as_float(v << 16); }
static __device__ __forceinline__ float unhi(unsigned v){ return __uint_as_float(v & 0xffff0000u); }

// ---------------- constants ----------------
#define CAP 10240          // binned slots per bucket (mean 8418, ~20 sigma)
#define EPB 16             // edges per thread in binscatter
#define CHUNK (256 * EPB)  // 4096 edges per block
#define PREPB 96           // prepw blocks in launch A
#define SORTCAP 9216       // LDS sort staging (8.7 sigma; global fallback beyond)

// ---------------- Launch A: prepw2 (blocks 0..95, self-detect) || binscatter ----------------
__global__ __launch_bounds__(256) void k_prep_scatter(
    const unsigned short* __restrict__ xprobe,
    const void* __restrict__ W1, const void* __restrict__ W2,
    int* __restrict__ flag,
    unsigned short* __restrict__ w1hi, unsigned short* __restrict__ w1lo,
    unsigned short* __restrict__ w2hi, unsigned short* __restrict__ w2lo,
    const int* __restrict__ ei, int* __restrict__ bucketCur,
    unsigned* __restrict__ binned, int E, int Etot){
  __shared__ int lcnt[256];
  __shared__ int lcur[256];
  int t = threadIdx.x;
  if (blockIdx.x < PREPB){
    // --- dtype probe: 512 halfwords of x. f32-as-bf16 trips ~123; true bf16 trips 0. ---
    if (t == 0) lcnt[0] = 0;
    __syncthreads();
    int bad = 0;
    for (int i = t; i < 512; i += 256){
      int e = (xprobe[i] >> 7) & 0xFF;
      if (e >= 133) bad++;
    }
    if (bad) atomicAdd(&lcnt[0], bad);
    __syncthreads();
    const int f = lcnt[0] > 8;
    if (blockIdx.x == 0 && t == 0) *flag = f;
    // --- prepw body ---
    int blk = blockIdx.x;
    const void* W; unsigned short *hi, *lo; int ncol, nct, tg;
    if (blk < 64){ W = W1; hi = w1hi; lo = w1lo; ncol = 128; nct = 8; tg = blk * 256 + t; }
    else         { W = W2; hi = w2hi; lo = w2lo; ncol = 64;  nct = 4; tg = (blk - 64) * 256 + t; }
    int j = tg & 7;
    int lane = (tg >> 3) & 63;
    int ct = (tg >> 9) % nct;
    int kc = tg / (512 * nct);
    int k = kc * 32 + ((lane >> 4) << 3) + j;
    int col = ct * 16 + (lane & 15);
    float w = ldf(W, (size_t)k * ncol + col, f);
    unsigned short h = f2bf(w);
    hi[tg] = h;
    lo[tg] = f2bf(w - bfval(h));
  } else {
    // --- binscatter body ---
    lcnt[t] = 0;
    __syncthreads();
    int base = (blockIdx.x - PREPB) * CHUNK;
    int vsrc[EPB], vdst[EPB];
#pragma unroll
    for (int k = 0; k < EPB; k++){
      int i = base + k * 256 + t;
      vdst[k] = -1;
      if (i < Etot){
        if (i < E){ vsrc[k] = ei[i]; vdst[k] = ei[E + i]; }
        else { vsrc[k] = i - E; vdst[k] = i - E; }
        atomicAdd(&lcnt[vdst[k] >> 8], 1);
      }
    }
    __syncthreads();
    lcur[t] = lcnt[t] ? atomicAdd(&bucketCur[t], lcnt[t]) : 0;
    __syncthreads();
#pragma unroll
    for (int k = 0; k < EPB; k++){
      if (vdst[k] >= 0){
        int b = vdst[k] >> 8;
        int p = atomicAdd(&lcur[b], 1);
        binned[(size_t)b * CAP + p] = (unsigned)vsrc[k] | ((unsigned)(vdst[k] & 255) << 24);
      }
    }
  }
}

// ---------------- Launch B: bucketsort (blocks 0..NBUCK-1) || gemm1m (MFMA bf16x3) ----------------
__global__ __launch_bounds__(256) void k_sort_gemm1(
    const int* __restrict__ bucketCur, const unsigned* __restrict__ binned,
    int* __restrict__ deg, int* __restrict__ offs, int* __restrict__ csr, int nbuck,
    const void* __restrict__ x,
    const unsigned short* __restrict__ whi, const unsigned short* __restrict__ wlo,
    const void* __restrict__ a_src1, const void* __restrict__ a_dst1,
    const int* __restrict__ flagp,
    unsigned* __restrict__ xh1p, float* __restrict__ ssrc1, float* __restrict__ sdst1, int n){
  __shared__ int smem[768 + SORTCAP];   // 39936 B: lcnt | lsc | lcur | lsrc
  int t = threadIdx.x;
  if ((int)blockIdx.x < nbuck){
    int* lcnt = smem;
    int* lsc  = smem + 256;
    int* lcur = smem + 512;
    int* lsrc = smem + 768;
    int b = blockIdx.x;
    int s0 = b * CAP;
    int cnt = bucketCur[b];
    int node0 = b << 8;
    lcnt[t] = 0;
    __syncthreads();
    for (int i = t; i < cnt; i += 256){
      unsigned v = binned[s0 + i];
      atomicAdd(&lcnt[v >> 24], 1);
    }
    __syncthreads();
    lsc[t] = lcnt[t];
    __syncthreads();
#pragma unroll
    for (int o = 1; o < 256; o <<= 1){
      int xv = (t >= o) ? lsc[t - o] : 0;
      __syncthreads();
      lsc[t] += xv;
      __syncthreads();
    }
    int excl = lsc[t] - lcnt[t];
    int node = node0 + t;
    if (node < n){ deg[node] = lcnt[t]; offs[node] = s0 + excl; }
    lcur[t] = excl;
    __syncthreads();
    if (cnt <= SORTCAP){
      for (int i = t; i < cnt; i += 256){
        unsigned v = binned[s0 + i];
        int p = atomicAdd(&lcur[v >> 24], 1);
        lsrc[p] = (int)(v & 0xFFFFFFu);
      }
      __syncthreads();
      for (int i = t; i < cnt; i += 256) csr[s0 + i] = lsrc[i];
    } else {
      for (int i = t; i < cnt; i += 256){
        unsigned v = binned[s0 + i];
        int p = atomicAdd(&lcur[v >> 24], 1);
        csr[s0 + p] = (int)(v & 0xFFFFFFu);
      }
    }
  } else {
    // --- gemm1m body ---
    const int f = *flagp;
    int lane = t & 63, w = t >> 6;
    int c16 = lane & 15, quad = lane >> 4;
    int nbw = (blockIdx.x - nbuck) * 64 + w * 16;
    int an = min(nbw + c16, n - 1);
    f32x4 acc[8];
#pragma unroll
    for (int ct = 0; ct < 8; ct++)
#pragma unroll
      for (int r = 0; r < 4; r++) acc[ct][r] = 0.f;

#pragma unroll
    for (int kc = 0; kc < 4; kc++){
      float av[8];
      short8 ahi, alo;
      if (f){
        const float* row = (const float*)x + (size_t)an * 128 + kc * 32 + quad * 8;
        float4 v0 = *(const float4*)row;
        float4 v1 = *(const float4*)(row + 4);
        av[0] = v0.x; av[1] = v0.y; av[2] = v0.z; av[3] = v0.w;
        av[4] = v1.x; av[5] = v1.y; av[6] = v1.z; av[7] = v1.w;
#pragma unroll
        for (int j = 0; j < 8; j++){
          unsigned short h = f2bf(av[j]);
          ahi[j] = (short)h;
          alo[j] = (short)f2bf(av[j] - bfval(h));
        }
      } else {
        const unsigned short* row = (const unsigned short*)x + (size_t)an * 128 + kc * 32 + quad * 8;
        uint4 v = *(const uint4*)row;
        ahi[0] = (short)(v.x & 0xffff); ahi[1] = (short)(v.x >> 16);
        ahi[2] = (short)(v.y & 0xffff); ahi[3] = (short)(v.y >> 16);
        ahi[4] = (short)(v.z & 0xffff); ahi[5] = (short)(v.z >> 16);
        ahi[6] = (short)(v.w & 0xffff); ahi[7] = (short)(v.w >> 16);
#pragma unroll
        for (int j = 0; j < 8; j++) alo[j] = 0;
      }
#pragma unroll
      for (int ct = 0; ct < 8; ct++){
        const short8 bhi = *(const short8*)(whi + (((size_t)(kc * 8 + ct) * 64 + lane) << 3));
        const short8 blo = *(const short8*)(wlo + (((size_t)(kc * 8 + ct) * 64 + lane) << 3));
        acc[ct] = __builtin_amdgcn_mfma_f32_16x16x32_bf16(ahi, blo, acc[ct], 0, 0, 0);
        acc[ct] = __builtin_amdgcn_mfma_f32_16x16x32_bf16(alo, bhi, acc[ct], 0, 0, 0);
        acc[ct] = __builtin_amdgcn_mfma_f32_16x16x32_bf16(ahi, bhi, acc[ct], 0, 0, 0);
      }
    }

    float as[8], ad[8];
#pragma unroll
    for (int ct = 0; ct < 8; ct++){
      as[ct] = ldf(a_src1, ct * 16 + c16, f);
      ad[ct] = ldf(a_dst1, ct * 16 + c16, f);
    }
    float vs0[4], vs1[4], vd0[4], vd1[4];
#pragma unroll
    for (int r = 0; r < 4; r++){
      float s0 = 0.f, s1 = 0.f, d0 = 0.f, d1 = 0.f;
#pragma unroll
      for (int ct = 0; ct < 4; ct++){
        s0 += acc[ct][r] * as[ct];         d0 += acc[ct][r] * ad[ct];
        s1 += acc[ct + 4][r] * as[ct + 4]; d1 += acc[ct + 4][r] * ad[ct + 4];
      }
      vs0[r] = qsum(s0); vs1[r] = qsum(s1);
      vd0[r] = qsum(d0); vd1[r] = qsum(d1);
    }
#pragma unroll
    for (int r = 0; r < 4; r++){
      int node = nbw + quad * 4 + r;
      if (node < n){
#pragma unroll
        for (int ct = 0; ct < 4; ct++)
          xh1p[(size_t)node * 64 + ct * 16 + c16] = packbf2(acc[ct][r], acc[ct + 4][r]);
      }
    }
    if (c16 == 0){
#pragma unroll
      for (int r = 0; r < 4; r++){
        int node = nbw + quad * 4 + r;
        if (node < n){
          ssrc1[node * 2]     = vs0[r];
          ssrc1[node * 2 + 1] = vs1[r];
          sdst1[node * 2]     = vd0[r];
          sdst1[node * 2 + 1] = vd1[r];
        }
      }
    }
  }
}

// ---------------- Layer-2 GEMM via MFMA: xh2 = h1(bf16) @ W2(hi+lo) + logits ----------------
__global__ __launch_bounds__(256) void k_gemm2m(
    const unsigned* __restrict__ h1p,
    const unsigned short* __restrict__ whi, const unsigned short* __restrict__ wlo,
    const void* __restrict__ a_src2, const void* __restrict__ a_dst2,
    const int* __restrict__ flagp,
    unsigned short* __restrict__ xh2b, float* __restrict__ ssrc2, float* __restrict__ sdst2, int n){
  const int f = *flagp;
  int t = threadIdx.x;
  int lane = t & 63, w = t >> 6;
  int c16 = lane & 15, quad = lane >> 4;
  int nbw = blockIdx.x * 64 + w * 16;
  int an = min(nbw + c16, n - 1);
  f32x4 acc[4];
#pragma unroll
  for (int ct = 0; ct < 4; ct++)
#pragma unroll
    for (int r = 0; r < 4; r++) acc[ct][r] = 0.f;

#pragma unroll
  for (int kc = 0; kc < 4; kc++){
    const uint4* hp = (const uint4*)h1p;
    uint4 v = hp[(size_t)an * 16 + kc * 4 + quad];
    short8 ahi;
    ahi[0] = (short)(v.x & 0xffff); ahi[1] = (short)(v.x >> 16);
    ahi[2] = (short)(v.y & 0xffff); ahi[3] = (short)(v.y >> 16);
    ahi[4] = (short)(v.z & 0xffff); ahi[5] = (short)(v.z >> 16);
    ahi[6] = (short)(v.w & 0xffff); ahi[7] = (short)(v.w >> 16);
#pragma unroll
    for (int ct = 0; ct < 4; ct++){
      const short8 bhi = *(const short8*)(whi + (((size_t)(kc * 4 + ct) * 64 + lane) << 3));
      const short8 blo = *(const short8*)(wlo + (((size_t)(kc * 4 + ct) * 64 + lane) << 3));
      acc[ct] = __builtin_amdgcn_mfma_f32_16x16x32_bf16(ahi, blo, acc[ct], 0, 0, 0);
      acc[ct] = __builtin_amdgcn_mfma_f32_16x16x32_bf16(ahi, bhi, acc[ct], 0, 0, 0);
    }
  }

  float as[4], ad[4];
#pragma unroll
  for (int ct = 0; ct < 4; ct++){
    as[ct] = ldf(a_src2, ct * 16 + c16, f);
    ad[ct] = ldf(a_dst2, ct * 16 + c16, f);
  }
  float vs[4], vd[4];
#pragma unroll
  for (int r = 0; r < 4; r++){
    float s = 0.f, d = 0.f;
#pragma unroll
    for (int ct = 0; ct < 4; ct++){
      s += acc[ct][r] * as[ct];
      d += acc[ct][r] * ad[ct];
    }
    vs[r] = qsum(s); vd[r] = qsum(d);
  }
#pragma unroll
  for (int r = 0; r < 4; r++){
    int node = nbw + quad * 4 + r;
    if (node < n){
#pragma unroll
      for (int ct = 0; ct < 4; ct++)
        xh2b[(size_t)node * 64 + ct * 16 + c16] = f2bf(acc[ct][r]);
    }
  }
  if (c16 == 0){
#pragma unroll
    for (int r = 0; r < 4; r++){
      int node = nbw + quad * 4 + r;
      if (node < n){ ssrc2[node] = vs[r]; sdst2[node] = vd[r]; }
    }
  }
}

// ---------------- Layer-1 aggregation: flat softmax, LDS-staged, half-wave gather x8 ----------------
__global__ __launch_bounds__(256) void k_agg1(
    const int* __restrict__ offs, const int* __restrict__ deg, const int* __restrict__ csr,
    const float2* __restrict__ ssrc, const float2* __restrict__ sdst,
    const unsigned* __restrict__ xh1p, const void* __restrict__ b1,
    const int* __restrict__ flagp, unsigned* __restrict__ h1p, int n){
  __shared__ float4 stg[4][64];   // wave-private (s, p0, p1, -) per chunk edge
  int wv = threadIdx.x >> 6;
  int wid = (int)(((size_t)blockIdx.x * blockDim.x + threadIdx.x) >> 6);
  int lane = threadIdx.x & 63;
  if (wid >= n) return;
  int st = offs[wid], d = deg[wid];
  int half = lane >> 5, u = lane & 31;
  float2 sd = sdst[wid];
  const uint2* xp = (const uint2*)xh1p;
  float Z0l = 0.f, Z1l = 0.f;
  float a0x = 0.f, a0y = 0.f, a1x = 0.f, a1y = 0.f;
  for (int base = 0; base < d; base += 64){
    int idx = base + lane;
    bool val = idx < d;
    int s = csr[st + (val ? idx : 0)];
    float2 sv = ssrc[s];
    float e0 = fminf(lrelu(sv.x + sd.x), 80.f);
    float e1 = fminf(lrelu(sv.y + sd.y), 80.f);
    float p0 = val ? __expf(e0) : 0.f;
    float p1 = val ? __expf(e1) : 0.f;
    Z0l += p0; Z1l += p1;
    // stage (s, p0, p1) once; broadcast via uniform ds_read_b128 (replaces 3 bpermutes/pair)
    float4 tv; tv.x = __uint_as_float((unsigned)s); tv.y = p0; tv.z = p1; tv.w = 0.f;
    stg[wv][lane] = tv;
    int cnt = min(64, d - base);
    int pairs = (cnt + 1) >> 1;
    for (int pj = 0; pj < pairs; pj += 8){
      int sj[8]; float q0v[8], q1v[8]; uint2 vv[8];
#pragma unroll
      for (int k = 0; k < 8; k++){
        int jj = ((pj + k) << 1) + half;
        float4 v = stg[wv][jj];
        sj[k] = (int)__float_as_uint(v.x);
        q0v[k] = v.y;
        q1v[k] = v.z;
      }
#pragma unroll
      for (int k = 0; k < 8; k++)
        vv[k] = xp[(size_t)(unsigned)sj[k] * 32 + u];
#pragma unroll
      for (int k = 0; k < 8; k++){
        a0x = fmaf(q0v[k], unlo(vv[k].x), a0x); a0y = fmaf(q0v[k], unlo(vv[k].y), a0y);
        a1x = fmaf(q1v[k], unhi(vv[k].x), a1x); a1y = fmaf(q1v[k], unhi(vv[k].y), a1y);
      }
    }
  }
  a0x += __shfl_xor(a0x, 32); a0y += __shfl_xor(a0y, 32);
  a1x += __shfl_xor(a1x, 32); a1y += __shfl_xor(a1y, 32);
  float Z0 = wsum(Z0l), Z1 = wsum(Z1l);
  const int f = *flagp;
  float Zh = half ? Z1 : Z0;
  float ax = half ? a1x : a0x;
  float ay = half ? a1y : a0y;
  float inv = 1.f / (Zh + 1e-16f);
  float bx = ldf(b1, half * 64 + 2 * u, f);
  float by = ldf(b1, half * 64 + 2 * u + 1, f);
  float ox = fmaxf(ax * inv + bx, 0.f);
  float oy = fmaxf(ay * inv + by, 0.f);
  // packed bf16 pair store: pair index c = half*32+u <-> channels {2c, 2c+1}
  h1p[(size_t)wid * 64 + half * 32 + u] = packbf2(ox, oy);
}

// ---------------- Layer-2 aggregation + fused heads: flat softmax, LDS-staged, half-wave x12 ----------------
// staging padded to 96 slots (slots 64..95 zero-weight) so unroll-12 never reads OOB.
__global__ __launch_bounds__(256) void k_agg2(
    const int* __restrict__ offs, const int* __restrict__ deg, const int* __restrict__ csr,
    const float* __restrict__ ssrc, const float* __restrict__ sdstA,
    const unsigned short* __restrict__ xh2b, const void* __restrict__ bias2,
    const void* __restrict__ Wm, const void* __restrict__ bm,
    const void* __restrict__ Wlos, const void* __restrict__ bl,
    const int* __restrict__ flagp, void* __restrict__ out, int n){
  __shared__ float2 stg[4][96];   // wave-private (s, p); [64..95] = zero pad
  int wv = threadIdx.x >> 6;
  int wid = (int)(((size_t)blockIdx.x * blockDim.x + threadIdx.x) >> 6);
  int lane = threadIdx.x & 63;
  if (wid >= n) return;
  int st = offs[wid], d = deg[wid];
  int half = lane >> 5, u = lane & 31;
  if (lane < 32){ float2 z; z.x = __uint_as_float(0u); z.y = 0.f; stg[wv][64 + lane] = z; }
  float sd = sdstA[wid];
  const unsigned* xp = (const unsigned*)xh2b;
  float Zl = 0.f, ax = 0.f, ay = 0.f;
  for (int base = 0; base < d; base += 64){
    int idx = base + lane;
    bool val = idx < d;
    int s = csr[st + (val ? idx : 0)];
    float e = fminf(lrelu(ssrc[s] + sd), 80.f);
    float p = val ? __expf(e) : 0.f;
    Zl += p;
    float2 tv; tv.x = __uint_as_float((unsigned)s); tv.y = p;
    stg[wv][lane] = tv;
    int cnt = min(64, d - base);
    int pairs = (cnt + 1) >> 1;
    for (int pj = 0; pj < pairs; pj += 12){
      int sj[12]; float qv[12]; unsigned vv[12];
#pragma unroll
      for (int k = 0; k < 12; k++){
        int jj = ((pj + k) << 1) + half;     // <= 2*(31+11)+1 = 85 < 96 (pad)
        float2 v = stg[wv][jj];
        sj[k] = (int)__float_as_uint(v.x);
        qv[k] = v.y;
      }
#pragma unroll
      for (int k = 0; k < 12; k++)
        vv[k] = xp[(size_t)(unsigned)sj[k] * 32 + u];
#pragma unroll
      for (int k = 0; k < 12; k++){
        ax = fmaf(qv[k], unlo(vv[k]), ax);
        ay = fmaf(qv[k], unhi(vv[k]), ay);
      }
    }
  }
  ax += __shfl_xor(ax, 32);
  ay += __shfl_xor(ay, 32);
  float Z = wsum(Zl);
  const int f = *flagp;
  float inv = 1.f / (Z + 1e-16f);
  float hx = fmaxf(ax * inv + ldf(bias2, 2 * u, f), 0.f);
  float hy = fmaxf(ay * inv + ldf(bias2, 2 * u + 1, f), 0.f);
  bool lo32 = (half == 0);
  float mo = wsum(lo32 ? hx * ldf(Wm, 2 * u, f) + hy * ldf(Wm, 2 * u + 1, f) : 0.f);
  float l0 = wsum(lo32 ? hx * ldf(Wlos, (2 * u) * 4 + 0, f) + hy * ldf(Wlos, (2 * u + 1) * 4 + 0, f) : 0.f);
  float l1 = wsum(lo32 ? hx * ldf(Wlos, (2 * u) * 4 + 1, f) + hy * ldf(Wlos, (2 * u + 1) * 4 + 1, f) : 0.f);
  float l2 = wsum(lo32 ? hx * ldf(Wlos, (2 * u) * 4 + 2, f) + hy * ldf(Wlos, (2 * u + 1) * 4 + 2, f) : 0.f);
  float l3 = wsum(lo32 ? hx * ldf(Wlos, (2 * u) * 4 + 3, f) + hy * ldf(Wlos, (2 * u + 1) * 4 + 3, f) : 0.f);
  if (lane == 0){
    float vm = mo + ldf(bm, 0, f);
    float v0 = l0 + ldf(bl, 0, f);
    float v1 = l1 + ldf(bl, 1, f);
    float v2 = l2 + ldf(bl, 2, f);
    float v3 = l3 + ldf(bl, 3, f);
    if (f){
      float* o = (float*)out;
      o[wid] = vm;
      float4 lv = make_float4(v0, v1, v2, v3);
      *(float4*)&o[n + wid * 4] = lv;
    } else {
      bf16* o = (bf16*)out;
      o[wid] = __float2bfloat16(vm);
      o[n + wid * 4 + 0] = __float2bfloat16(v0); o[n + wid * 4 + 1] = __float2bfloat16(v1);
      o[n + wid * 4 + 2] = __float2bfloat16(v2); o[n + wid * 4 + 3] = __float2bfloat16(v3);
    }
  }
}

extern "C" void kernel_launch(void* const* d_in, const int* in_sizes, int n_in,
                              void* d_out, int out_size, void* d_ws, size_t ws_size,
                              hipStream_t stream){
  const void* x      = d_in[0];
  const int*  ei     = (const int*)d_in[1];
  const void* W1     = d_in[2];
  const void* a_src1 = d_in[3];
  const void* a_dst1 = d_in[4];
  const void* b1     = d_in[5];
  const void* W2     = d_in[6];
  const void* a_src2 = d_in[7];
  const void* a_dst2 = d_in[8];
  const void* bias2  = d_in[9];
  const void* Wm     = d_in[10];
  const void* bm     = d_in[11];
  const void* Wlos   = d_in[12];
  const void* bl     = d_in[13];

  const int N = in_sizes[0] / 128;
  const int E = in_sizes[1] / 2;
  const int Etot = E + N;
  const int NBUCK = (N + 255) >> 8;

  char* base = (char*)d_ws;
  size_t off = 0;
  auto alloc = [&](size_t bytes) -> void* {
    void* r = base + off;
    off += (bytes + 255) & ~(size_t)255;
    return r;
  };
  int*      flag  = (int*)alloc(256);
  unsigned* xh1p  = (unsigned*)alloc((size_t)N * 64 * 4);   // packed bf16x2 (both heads)
  unsigned* h1p   = (unsigned*)alloc((size_t)N * 64 * 4);   // h1 packed bf16 pairs
  float*    ssrc1 = (float*)alloc((size_t)N * 2 * 4);
  float*    sdst1 = (float*)alloc((size_t)N * 2 * 4);
  float*    ssrc2 = (float*)alloc((size_t)N * 4);
  float*    sdst2 = (float*)alloc((size_t)N * 4);
  int*      deg    = (int*)alloc((size_t)N * 4);
  int*      offsb  = (int*)alloc((size_t)N * 4);
  unsigned* binned = (unsigned*)alloc((size_t)NBUCK * CAP * 4);
  int*      csr    = (int*)alloc((size_t)NBUCK * CAP * 4);
  int*      bucketCur = (int*)alloc(1024);
  unsigned short* w1hi = (unsigned short*)alloc(16384 * 2);
  unsigned short* w1lo = (unsigned short*)alloc(16384 * 2);
  unsigned short* w2hi = (unsigned short*)alloc(8192 * 2);
  unsigned short* w2lo = (unsigned short*)alloc(8192 * 2);
  unsigned short* xh2b = (unsigned short*)xh1p;   // reuse after k_agg1

  const int nchunk = (Etot + CHUNK - 1) / CHUNK;
  const int ngemm1 = (N + 63) / 64;

  // zero bucket cursors (stream op, capture-safe)
  hipMemsetAsync(bucketCur, 0, (size_t)NBUCK * 4, stream);

  // Launch A: prepw2 (w/ inline dtype probe, flag publish) || binscatter
  k_prep_scatter<<<PREPB + nchunk, 256, 0, stream>>>(
      (const unsigned short*)x, W1, W2, flag, w1hi, w1lo, w2hi, w2lo,
      ei, bucketCur, binned, E, Etot);

  // Launch B: bucketsort || gemm1m
  k_sort_gemm1<<<NBUCK + ngemm1, 256, 0, stream>>>(
      bucketCur, binned, deg, offsb, csr, NBUCK,
      x, w1hi, w1lo, a_src1, a_dst1, flag, xh1p, ssrc1, sdst1, N);

  // Layer 1 aggregation (outputs packed bf16 h1)
  k_agg1<<<(N + 3) / 4, 256, 0, stream>>>(offsb, deg, csr, (const float2*)ssrc1, (const float2*)sdst1,
                                          xh1p, b1, flag, h1p, N);

  // Layer 2
  k_gemm2m<<<(N + 63) / 64, 256, 0, stream>>>(h1p, w2hi, w2lo, a_src2, a_dst2, flag, xh2b, ssrc2, sdst2, N);
  k_agg2<<<(N + 3) / 4, 256, 0, stream>>>(offsb, deg, csr, ssrc2, sdst2, xh2b, bias2,
                                          Wm, bm, Wlos, bl, flag, d_out, N);
}